// Round 9
// baseline (6197.231 us; speedup 1.0000x reference)
//
#include <hip/hip_runtime.h>

// LightGCN: out = (e0 + A e0 + A^2 e0 + A^3 e0) / 4 over 150K nodes, 4.8M COO edges, D=64.
// R15: ELIMINATE the second reorganization stage. Measured across R11-R14: any
// stage-2 (row sort / slice gather / window scatter) costs 90-126us, and stage-1
// LDS sort is a ~100-110us fixed cost insensitive to run length. New structure:
//   prelude -> stageP (ONE LDS counting sort into 586 bins of 256 rows, 84B runs)
//   -> spmm_acc x3: block = one bin, 64KB LDS fp32 accumulator acc[256][64].
// spmm_acc consumes the bin's edge stream in ARBITRARY order: wave-uniform s_load
// records (R8's scalar-stream trick), 64-lane gather x[col] (one 128B line -- same
// traffic as the proven 92us kernel), ds_add_f32 into acc[rowLocal][lane]
// (banks = lane%32, conflict-free; LDS atomic cost hidden under gather latency).
// 1024-thr blocks x2/CU = 32 waves/CU (> R8's 24). No desc, no CSR, no 16-padding.
// Row-internal order arbitrary = commutative fp32 accumulation (proven tolerant).

#define N_USERS 100000
#define N_ITEMS 50000
#define N_NODES 150000
#define N_EDGES 4800000
#define EMB_DIM 64

typedef unsigned short u16;
typedef unsigned int   u32;

constexpr int NODE_FLOATS  = N_NODES * EMB_DIM;      // 9,600,000
constexpr int NODE_FLOAT4S = NODE_FLOATS / 4;        // 2,400,000
constexpr int USER_FLOAT4S = N_USERS * EMB_DIM / 4;  // 1,600,000

constexpr int BINSH = 8;                             // bin shift (256 rows)
constexpr int BINR  = 256;                           // rows per bin
constexpr int NBIN  = (N_NODES + BINR - 1) / BINR;   // 586 bins
constexpr int PCAP  = 9216;                          // records/bin cap (mean 8191, +11.3 sigma)
constexpr int EPB   = 6144;                          // edges per stageP block
constexpr int ABLK  = (N_EDGES + EPB - 1) / EPB;     // 782

// ---- bf16 helpers (RNE) ----
static __device__ __forceinline__ float bf2f(u16 b) {
    return __uint_as_float(((u32)b) << 16);
}
static __device__ __forceinline__ u16 f2bf(float f) {
    u32 u = __float_as_uint(f);
    return (u16)((u + 0x7FFFu + ((u >> 16) & 1u)) >> 16);
}

// ---------------- prelude: buf0 = bf16(e0), pcnt = 0 ----------------
__global__ void prelude_kernel(const float* __restrict__ user_emb,
                               const float* __restrict__ item_emb,
                               u16* __restrict__ emb,
                               int* __restrict__ pcnt) {
    int i = blockIdx.x * blockDim.x + threadIdx.x;
    if (i < 1024) pcnt[i] = 0;
    if (i >= NODE_FLOAT4S) return;
    float4 v = (i < USER_FLOAT4S) ? ((const float4*)user_emb)[i]
                                  : ((const float4*)item_emb)[i - USER_FLOAT4S];
    ushort4 o;
    o.x = f2bf(v.x); o.y = f2bf(v.y); o.z = f2bf(v.z); o.w = f2bf(v.w);
    ((ushort4*)emb)[i] = o;
}

// ---------------- stage P: LDS counting sort into 586 bins (256 rows each) ------
// Record uint2{ key = (row&255)<<18 | col , val = bf16 }. Runs of mean 10.5 recs
// (84B) flushed coalesced to part_buf[bin*PCAP + cursor ..). One global atomic
// per (block,bin).
__global__ void stageP_kernel(const int* __restrict__ rows,
                              const int* __restrict__ cols,
                              const float* __restrict__ vals,
                              int* __restrict__ pcnt,
                              uint2* __restrict__ part_buf) {
    __shared__ u32 lkey[EPB];          // 24 KB
    __shared__ u16 lval[EPB];          // 12 KB
    __shared__ u16 lbkt[EPB];          // 12 KB
    __shared__ int hist[NBIN], hstart[NBIN], hcur[NBIN], gbase[NBIN];  // 9.4 KB
    __shared__ int ws4[4];

    const int tid  = threadIdx.x;
    const int base = blockIdx.x * EPB;
    const int cnt  = min(EPB, N_EDGES - base);

    for (int i = tid; i < NBIN; i += 256) hist[i] = 0;
    __syncthreads();

    for (int k = 0; k < EPB / 256; k += 8) {
        int rbuf[8];
        #pragma unroll
        for (int q = 0; q < 8; ++q) {
            int idx = (k + q) * 256 + tid;
            rbuf[q] = (idx < cnt) ? rows[base + idx] : -1;
        }
        #pragma unroll
        for (int q = 0; q < 8; ++q)
            if (rbuf[q] >= 0) atomicAdd(&hist[rbuf[q] >> BINSH], 1);
    }
    __syncthreads();

    const int lane = tid & 63, wave = tid >> 6;
    int carry = 0;
    for (int c0 = 0; c0 < NBIN; c0 += 256) {
        int i = c0 + tid;
        int v = (i < NBIN) ? hist[i] : 0;
        int incl = v;
        #pragma unroll
        for (int off = 1; off < 64; off <<= 1) {
            int t = __shfl_up(incl, off);
            if (lane >= off) incl += t;
        }
        if (lane == 63) ws4[wave] = incl;
        __syncthreads();
        int wpref = 0, tot = 0;
        #pragma unroll
        for (int w = 0; w < 4; ++w) { int s = ws4[w]; if (w < wave) wpref += s; tot += s; }
        int excl = carry + wpref + incl - v;
        if (i < NBIN) { hstart[i] = excl; hcur[i] = excl; }
        carry += tot;
        __syncthreads();
    }

    for (int k = 0; k < EPB / 256; k += 8) {
        int rb[8], cb[8]; float vb[8];
        #pragma unroll
        for (int q = 0; q < 8; ++q) {
            int idx = (k + q) * 256 + tid;
            if (idx < cnt) { rb[q] = rows[base + idx]; cb[q] = cols[base + idx]; vb[q] = vals[base + idx]; }
            else rb[q] = -1;
        }
        #pragma unroll
        for (int q = 0; q < 8; ++q) {
            if (rb[q] < 0) continue;
            int b = rb[q] >> BINSH;
            int p = atomicAdd(&hcur[b], 1);
            lkey[p] = ((u32)(rb[q] & (BINR - 1)) << 18) | (u32)cb[q];
            lval[p] = f2bf(vb[q]);
            lbkt[p] = (u16)b;
        }
    }
    __syncthreads();

    for (int i = tid; i < NBIN; i += 256) {
        int n = hist[i];
        if (n) {
            int p = atomicAdd(&pcnt[i], n);
            gbase[i] = (p + n <= PCAP) ? p : -1;   // +11 sigma: statistically never
        }
    }
    __syncthreads();

    // long-run coalesced flush (runs contiguous in LDS and in global)
    for (int i = tid; i < cnt; i += 256) {
        int b  = lbkt[i];
        int gb = gbase[b];
        if (gb >= 0)
            part_buf[(size_t)b * PCAP + gb + (i - hstart[b])] =
                make_uint2(lkey[i], (u32)lval[i]);
    }
}

// ------- SpMM: block = one 256-row bin, 64KB LDS fp32 accumulator -------
// Edge stream consumed in arbitrary order: 16-edge groups, wave-uniform s_load
// records, 64-lane gather of x[col] (one 128B line/edge), ds_add_f32 into
// acc[rowLocal][lane] (banks = lane%32, conflict-free). 16 waves/block, 2
// blocks/CU = 32 waves/CU. Flush coalesced.
// layers 1/2: y = A x (bf16). layer 3 (y==null): out = (e0 + y1 + y2 + A x)/4 fp32.
__global__ __launch_bounds__(1024, 8)
void spmm_acc_kernel(const int* __restrict__ pcnt,
                     const uint2* __restrict__ part_buf,
                     const u16* __restrict__ x,
                     u16* __restrict__ y,
                     const u16* __restrict__ e0,
                     const u16* __restrict__ y1,
                     const u16* __restrict__ y2,
                     float* __restrict__ out) {
    __shared__ float acc[BINR * EMB_DIM];              // 65536 B
    const int tid  = threadIdx.x;
    const int lane = tid & 63;
    const int wv   = __builtin_amdgcn_readfirstlane(tid >> 6);   // 0..15
    const int b    = blockIdx.x;

    #pragma unroll
    for (int i = 0; i < (BINR * EMB_DIM) / 1024; ++i)
        acc[i * 1024 + tid] = 0.f;
    __syncthreads();

    const int n  = min(pcnt[b], PCAP);
    const int ng = n >> 4;                             // full 16-edge groups
    const uint2* __restrict__ rp = part_buf + (size_t)b * PCAP;
    const u16*   __restrict__ xl = x + lane;

    const int gbeg = (ng * wv) >> 4;
    const int gend = (ng * (wv + 1)) >> 4;

    for (int g = gbeg; g < gend; ++g) {
        u32 key[16], val[16];
        #pragma unroll
        for (int k = 0; k < 16; ++k) {                 // wave-uniform s_load stream
            uint2 r = rp[g * 16 + k];
            key[k] = r.x; val[k] = r.y;
        }
        u32 xv[16];
        #pragma unroll
        for (int k = 0; k < 16; ++k)                   // 16 independent 1-VGPR gathers
            xv[k] = (u32)xl[(size_t)(key[k] & 0x3FFFFu) * EMB_DIM];
        #pragma unroll
        for (int k = 0; k < 16; ++k) {
            float vv = __uint_as_float(val[k] << 16);
            float xf = __uint_as_float(xv[k] << 16);
            atomicAdd(&acc[((key[k] >> 18) << 6) + lane], vv * xf);
        }
    }
    if (wv == 15) {                                    // tail (< 16 edges)
        for (int i = ng * 16; i < n; ++i) {
            uint2 r = rp[i];
            float vv = __uint_as_float(r.y << 16);
            u32 xvv  = (u32)xl[(size_t)(r.x & 0x3FFFFu) * EMB_DIM];
            atomicAdd(&acc[((r.x >> 18) << 6) + lane], vv * __uint_as_float(xvv << 16));
        }
    }
    __syncthreads();

    const int rbase = b * BINR;
    if (y) {
        for (int i = tid; i < BINR * EMB_DIM; i += 1024) {
            int row = rbase + (i >> 6);
            if (row < N_NODES)
                y[(size_t)row * EMB_DIM + (i & 63)] = f2bf(acc[i]);
        }
    } else {
        for (int i = tid; i < BINR * EMB_DIM; i += 1024) {
            int row = rbase + (i >> 6);
            if (row < N_NODES) {
                size_t o = (size_t)row * EMB_DIM + (i & 63);
                out[o] = (bf2f(e0[o]) + bf2f(y1[o]) + bf2f(y2[o]) + acc[i]) * 0.25f;
            }
        }
    }
}

// ---------------- fallback (R0 atomic path) ----------------
__global__ void init3_kernel(const float* __restrict__ user_emb,
                             const float* __restrict__ item_emb,
                             float* __restrict__ emb,
                             float* __restrict__ acc,
                             float* __restrict__ nxt) {
    int i = blockIdx.x * blockDim.x + threadIdx.x;
    if (i >= NODE_FLOAT4S) return;
    float4 v = (i < USER_FLOAT4S) ? ((const float4*)user_emb)[i]
                                  : ((const float4*)item_emb)[i - USER_FLOAT4S];
    ((float4*)emb)[i] = v;
    ((float4*)acc)[i] = v;
    ((float4*)nxt)[i] = make_float4(0.f, 0.f, 0.f, 0.f);
}

__global__ void spmm_atomic_kernel(const int* __restrict__ rows,
                                   const int* __restrict__ cols,
                                   const float* __restrict__ vals,
                                   const float* __restrict__ x,
                                   float* __restrict__ y) {
    unsigned tid = blockIdx.x * blockDim.x + threadIdx.x;
    unsigned e  = tid >> 4;
    unsigned d4 = tid & 15u;
    if (e >= N_EDGES) return;
    int r = rows[e]; int c = cols[e]; float v = vals[e];
    float4 xv = ((const float4*)(x + (size_t)c * EMB_DIM))[d4];
    float* yp = y + (size_t)r * EMB_DIM + d4 * 4;
    atomicAdd(yp + 0, v * xv.x);
    atomicAdd(yp + 1, v * xv.y);
    atomicAdd(yp + 2, v * xv.z);
    atomicAdd(yp + 3, v * xv.w);
}

__global__ void acc_kernel(float* __restrict__ acc, const float* __restrict__ nxt,
                           float* __restrict__ zbuf, int do_zero, float scale) {
    int i = blockIdx.x * blockDim.x + threadIdx.x;
    if (i >= NODE_FLOAT4S) return;
    float4 a = ((float4*)acc)[i];
    float4 n = ((const float4*)nxt)[i];
    a.x = (a.x + n.x) * scale; a.y = (a.y + n.y) * scale;
    a.z = (a.z + n.z) * scale; a.w = (a.w + n.w) * scale;
    ((float4*)acc)[i] = a;
    if (do_zero) ((float4*)zbuf)[i] = make_float4(0.f, 0.f, 0.f, 0.f);
}

extern "C" void kernel_launch(void* const* d_in, const int* in_sizes, int n_in,
                              void* d_out, int out_size, void* d_ws, size_t ws_size,
                              hipStream_t stream) {
    const int*   rows     = (const int*)d_in[0];
    const int*   cols     = (const int*)d_in[1];
    const float* vals     = (const float*)d_in[2];
    const float* user_emb = (const float*)d_in[3];
    const float* item_emb = (const float*)d_in[4];
    float* out = (float*)d_out;

    // ws layout (u32 units):
    //   buf0 bf16 [4.8M] | buf1 bf16 [4.8M] | buf2 bf16 [4.8M]
    //   | part_buf uint2 [586*9216 recs = 10,801,152 u32]  (live ALL layers)
    //   | pcnt [1024]
    constexpr size_t U_BUF  = (size_t)NODE_FLOATS / 2;           // 4,800,000
    constexpr size_t U_PART = (size_t)NBIN * PCAP * 2;           // 10,801,152
    size_t need_u32 = 3 * U_BUF + U_PART + 1024;                 // 25,202,176 (~100.8 MB)

    const int EW_BLOCKS = (NODE_FLOAT4S + 255) / 256;

    if (ws_size >= need_u32 * 4) {
        u32*   W        = (u32*)d_ws;
        u16*   buf0     = (u16*)W;
        u16*   buf1     = (u16*)(W + U_BUF);
        u16*   buf2     = (u16*)(W + 2 * U_BUF);
        uint2* part_buf = (uint2*)(W + 3 * U_BUF);
        int*   pcnt     = (int*)(W + 3 * U_BUF + U_PART);

        prelude_kernel<<<EW_BLOCKS, 256, 0, stream>>>(user_emb, item_emb, buf0, pcnt);
        stageP_kernel<<<ABLK, 256, 0, stream>>>(rows, cols, vals, pcnt, part_buf);

        spmm_acc_kernel<<<NBIN, 1024, 0, stream>>>(pcnt, part_buf,
                                                   buf0, buf1, nullptr, nullptr, nullptr, nullptr);
        spmm_acc_kernel<<<NBIN, 1024, 0, stream>>>(pcnt, part_buf,
                                                   buf1, buf2, nullptr, nullptr, nullptr, nullptr);
        spmm_acc_kernel<<<NBIN, 1024, 0, stream>>>(pcnt, part_buf,
                                                   buf2, nullptr, buf0, buf1, buf2, out);
    } else {
        // fallback: R0 atomic path
        float* buf0 = (float*)d_ws;
        float* buf1 = buf0 + NODE_FLOATS;
        const int SPMM_BLOCKS = (int)(((size_t)N_EDGES * 16 + 255) / 256);
        init3_kernel<<<EW_BLOCKS, 256, 0, stream>>>(user_emb, item_emb, buf0, out, buf1);
        float* prev = buf0; float* next = buf1;
        for (int layer = 0; layer < 3; ++layer) {
            spmm_atomic_kernel<<<SPMM_BLOCKS, 256, 0, stream>>>(rows, cols, vals, prev, next);
            if (layer < 2) acc_kernel<<<EW_BLOCKS, 256, 0, stream>>>(out, next, prev, 1, 1.0f);
            else           acc_kernel<<<EW_BLOCKS, 256, 0, stream>>>(out, next, prev, 0, 0.25f);
            float* t = prev; prev = next; next = t;
        }
    }
}

// Round 10
// 502.463 us; speedup vs baseline: 12.3337x; 12.3337x over previous
//
#include <hip/hip_runtime.h>

// LightGCN: out = (e0 + A e0 + A^2 e0 + A^3 e0) / 4 over 150K nodes, 4.8M COO edges, D=64.
// R16: revert to R11 (best measured 490.7us) + three low-risk prep cuts:
//  (1) e0->bf16 conversion FUSED into stageA2 (independent work, hides under the
//      sort's latency stalls; removes one full-grid pass).
//  (2) bx_pos/csr_cursor init via hipMemsetAsync (capture-safe; harness reset()
//      uses it) with 0-based segment frontiers -- no init kernel, no race.
//  (3) EPB 6144 -> 4096: A2 LDS 66.8 -> 50.8KB -> 3 blocks/CU (12 waves, was 8);
//      1172 blocks smooths the tail.
// spmm = R8 kernel verbatim -- the ONLY structure of 5 tried (R8/R9/R10/R15/atomic)
// that sustains gather MLP (~3.9TB/s L2-miss path). R15's LDS-accumulator variant
// collapsed to 174GB/s (long waves + SMEM stream serialized the gathers). B2,
// bucket geometry (1172x128), CAP1, desc format, ws layout: R11 verbatim.

#define N_USERS 100000
#define N_ITEMS 50000
#define N_NODES 150000
#define N_EDGES 4800000
#define EMB_DIM 64

typedef unsigned short u16;
typedef unsigned int   u32;

constexpr int NODE_FLOATS  = N_NODES * EMB_DIM;      // 9,600,000
constexpr int NODE_FLOAT4S = NODE_FLOATS / 4;        // 2,400,000
constexpr int USER_FLOAT4S = N_USERS * EMB_DIM / 4;  // 1,600,000

constexpr int BSH  = 7;                              // bucket shift (128 rows)
constexpr int BRW  = 128;                            // rows per bucket
constexpr int NB   = (N_NODES + BRW - 1) / BRW;      // 1172 buckets
constexpr int NXG  = 8;                              // XCD groups (blockIdx & 7)
constexpr int SEG  = NB * NXG;                       // 9376 (bucket,x) segments
constexpr int CAP1 = 704;                            // per-segment cap (mean 512, +8.5 sigma)
constexpr int EPB  = 4096;                           // edges per stageA2 block (was 6144)
constexpr int ABLK2 = (N_EDGES + EPB - 1) / EPB;     // 1172
constexpr int CONV4 = 2048;                          // float4s converted per A2 block (1172*2048 >= 2.4M)
constexpr int SB_CAP2 = 5760;                        // stageB2 LDS records, PADDED (mean 5082, +8 sigma)
constexpr int CSR_CAP = 6000000;                     // padded CSR entries (mean 5.95M, +16 sigma)

// ---- bf16 helpers (RNE) ----
static __device__ __forceinline__ float bf2f(u16 b) {
    return __uint_as_float(((u32)b) << 16);
}
static __device__ __forceinline__ u16 f2bf(float f) {
    u32 u = __float_as_uint(f);
    return (u16)((u + 0x7FFFu + ((u >> 16) & 1u)) >> 16);
}

// ---------------- stage A2: LDS counting sort + fused e0->bf16 conversion --------
// Conversion: block a converts float4s [a*CONV4, a*CONV4+CONV4) of e0 -> buf0.
// Sort: block a's 4096 edges histogrammed/sorted by 128-row bucket in LDS, then
// flushed to 0-based segment frontiers (bx_pos zeroed by hipMemsetAsync).
__global__ void stageA2_kernel(const int* __restrict__ rows,
                               const int* __restrict__ cols,
                               const float* __restrict__ vals,
                               const float* __restrict__ user_emb,
                               const float* __restrict__ item_emb,
                               u16* __restrict__ emb,
                               int* __restrict__ bx_pos,
                               u32* __restrict__ stage_key,
                               u16* __restrict__ stage_val) {
    __shared__ u32 lkey[EPB];          // 16 KB
    __shared__ u16 lval[EPB];          // 8 KB
    __shared__ u16 lbkt[EPB];          // 8 KB
    __shared__ int hist[NB];           // 4.58 KB x4 = 18.3 KB
    __shared__ int hstart[NB];
    __shared__ int hcur[NB];
    __shared__ int gbase[NB];
    __shared__ int ws4[4];

    const int tid  = threadIdx.x;
    const int base = blockIdx.x * EPB;
    const int cnt  = min(EPB, N_EDGES - base);
    const int x    = blockIdx.x & (NXG - 1);

    // ---- fused e0 -> bf16 conversion (independent of the sort) ----
    {
        const int cbase = blockIdx.x * CONV4;
        #pragma unroll
        for (int q = 0; q < CONV4 / 256; ++q) {
            int i = cbase + q * 256 + tid;
            if (i < NODE_FLOAT4S) {
                float4 v = (i < USER_FLOAT4S)
                    ? ((const float4*)user_emb)[i]
                    : ((const float4*)item_emb)[i - USER_FLOAT4S];
                ushort4 o;
                o.x = f2bf(v.x); o.y = f2bf(v.y); o.z = f2bf(v.z); o.w = f2bf(v.w);
                ((ushort4*)emb)[i] = o;
            }
        }
    }

    for (int i = tid; i < NB; i += 256) hist[i] = 0;
    __syncthreads();

    for (int k = 0; k < EPB / 256; k += 8) {
        int rbuf[8];
        #pragma unroll
        for (int q = 0; q < 8; ++q) {
            int idx = (k + q) * 256 + tid;
            rbuf[q] = (idx < cnt) ? rows[base + idx] : -1;
        }
        #pragma unroll
        for (int q = 0; q < 8; ++q)
            if (rbuf[q] >= 0) atomicAdd(&hist[rbuf[q] >> BSH], 1);
    }
    __syncthreads();

    const int lane = tid & 63, wave = tid >> 6;
    int carry = 0;
    for (int c0 = 0; c0 < NB; c0 += 256) {
        int i = c0 + tid;
        int v = (i < NB) ? hist[i] : 0;
        int incl = v;
        #pragma unroll
        for (int off = 1; off < 64; off <<= 1) {
            int t = __shfl_up(incl, off);
            if (lane >= off) incl += t;
        }
        if (lane == 63) ws4[wave] = incl;
        __syncthreads();
        int wpref = 0, tot = 0;
        #pragma unroll
        for (int w = 0; w < 4; ++w) { int s = ws4[w]; if (w < wave) wpref += s; tot += s; }
        int excl = carry + wpref + incl - v;
        if (i < NB) { hstart[i] = excl; hcur[i] = excl; }
        carry += tot;
        __syncthreads();
    }

    for (int k = 0; k < EPB / 256; k += 8) {
        int rb[8], cb[8]; float vb[8];
        #pragma unroll
        for (int q = 0; q < 8; ++q) {
            int idx = (k + q) * 256 + tid;
            if (idx < cnt) { rb[q] = rows[base + idx]; cb[q] = cols[base + idx]; vb[q] = vals[base + idx]; }
            else rb[q] = -1;
        }
        #pragma unroll
        for (int q = 0; q < 8; ++q) {
            if (rb[q] < 0) continue;
            int b = rb[q] >> BSH;
            int p = atomicAdd(&hcur[b], 1);
            lkey[p] = ((u32)(rb[q] & (BRW - 1)) << 24) | (u32)cb[q];
            lval[p] = f2bf(vb[q]);
            lbkt[p] = (u16)b;
        }
    }
    __syncthreads();

    for (int i = tid; i < NB; i += 256) {
        int n = hist[i];
        if (n) {
            int seg = i * NXG + x;
            int p = atomicAdd(&bx_pos[seg * 16], n);          // 0-based frontier
            gbase[i] = (p + n <= CAP1) ? (seg * CAP1 + p) : -1;
        }
    }
    __syncthreads();

    for (int i = tid; i < cnt; i += 256) {
        int b  = lbkt[i];
        int gb = gbase[b];
        if (gb >= 0) {
            int d = gb + (i - hstart[b]);
            stage_key[d] = lkey[i];
            stage_val[d] = lval[i];
        }
    }
}

// -------- stage B2: per-bucket row sort in LDS, 16-PADDED contiguous CSR --------
// 128-row buckets -> 1172 blocks x ~37.6 KB LDS = 4 blocks/CU. Each row's segment
// padded to a multiple of 16 with (col=0,val=0) dummies so spmm has no remainder
// path. desc[row] = (abs_beg << 8) | padded_cnt (mult of 16, cap 240).
__global__ void stageB2_kernel(const int* __restrict__ bx_pos,
                               const u32* __restrict__ stage_key,
                               const u16* __restrict__ stage_val,
                               int* __restrict__ csr_cursor,
                               u32* __restrict__ csr_col,
                               u16* __restrict__ csr_val,
                               u32* __restrict__ desc) {
    __shared__ u32 skey[SB_CAP2];      // 23 KB (col only)
    __shared__ u16 sval[SB_CAP2];      // 11.5 KB
    __shared__ int rhist[256], rpad0[256], rcur[256];   // bins 0..127 used
    __shared__ int ws4[4];
    __shared__ int sbase_sh;

    const int b   = blockIdx.x;
    const int tid = threadIdx.x;
    rhist[tid] = 0;
    __syncthreads();

    for (int xx = 0; xx < NXG; ++xx) {
        int seg = b * NXG + xx;
        int sb  = seg * CAP1;
        int n   = min(bx_pos[seg * 16], CAP1);
        for (int i = tid; i < n; i += 256)
            atomicAdd(&rhist[stage_key[sb + i] >> 24], 1);
    }
    __syncthreads();

    const int lane = tid & 63, wave = tid >> 6;
    int v  = rhist[tid];
    int vp = (v + 15) & ~15;           // padded count (zero for unused bins 128..255)
    int incl = vp;
    #pragma unroll
    for (int off = 1; off < 64; off <<= 1) {
        int t = __shfl_up(incl, off);
        if (lane >= off) incl += t;
    }
    if (lane == 63) ws4[wave] = incl;
    __syncthreads();
    int wpref = 0, total = 0;
    #pragma unroll
    for (int w = 0; w < 4; ++w) { int s = ws4[w]; if (w < wave) wpref += s; total += s; }
    int excl = wpref + incl - vp;
    rpad0[tid] = excl;
    rcur[tid]  = excl;
    if (tid == 0) sbase_sh = atomicAdd(csr_cursor, total);
    __syncthreads();

    const int tcap = min(total, SB_CAP2);
    // pre-fill with dummies (col 0, val 0) -> padded slots contribute 0 in spmm
    for (int i = tid; i < tcap; i += 256) { skey[i] = 0u; sval[i] = 0; }
    __syncthreads();

    for (int xx = 0; xx < NXG; ++xx) {
        int seg = b * NXG + xx;
        int sb  = seg * CAP1;
        int n   = min(bx_pos[seg * 16], CAP1);
        for (int i = tid; i < n; i += 256) {
            u32 key = stage_key[sb + i];
            u16 val = stage_val[sb + i];
            int p = atomicAdd(&rcur[key >> 24], 1);
            if (p < SB_CAP2) { skey[p] = key & 0x00FFFFFFu; sval[p] = val; }
        }
    }
    __syncthreads();

    const int sbase = sbase_sh;
    for (int i = tid; i < tcap; i += 256) {
        int g = sbase + i;
        if (g < CSR_CAP) { csr_col[g] = skey[i]; csr_val[g] = sval[i]; }
    }
    if (tid < BRW) {
        int grow = b * BRW + tid;
        if (grow < N_NODES) {
            int cp = vp; if (cp > 240) cp = 240;
            desc[grow] = ((u32)(sbase + rpad0[tid]) << 8) | (u32)cp;
        }
    }
}

// ------- CSR SpMM: ONE ROW PER WAVE (64 lanes = 64 embedding elements) -------
// R8's kernel verbatim (best measured: 91.4us/dispatch, occ 75%). The gather loop
// is pinned at ~3.9 TB/s L2-miss-path throughput (R8/R9/R10 invariance) -- the
// pattern's memory-side ceiling. R15 proved the structure itself (short waves,
// scalar streams, 16-gather bursts) is load-bearing. Do not touch.
// layers 1/2: y = A x (bf16). layer 3 (y==null): out = (e0 + y1 + y2 + A x)/4 fp32.
__global__ __launch_bounds__(256, 8)
void spmm_rw_kernel(const u32* __restrict__ desc,
                    const u32* __restrict__ csr_col,
                    const u16* __restrict__ csr_val,
                    const u16* __restrict__ x,
                    u16* __restrict__ y,
                    const u16* __restrict__ e0,
                    const u16* __restrict__ y1,
                    const u16* __restrict__ y2,
                    float* __restrict__ out) {
    const int lane = threadIdx.x & 63;
    const int wid  = __builtin_amdgcn_readfirstlane(threadIdx.x >> 6);
    const int row  = blockIdx.x * 4 + wid;
    if (row >= N_NODES) return;

    const u32 d   = desc[row];
    const int beg = (int)(d >> 8);
    const int nch = (int)(d & 255u) >> 4;

    const u32* __restrict__ pc = csr_col + beg;
    const u32* __restrict__ pv = ((const u32*)csr_val) + (beg >> 1);  // beg is even (16-aligned)
    const u16* __restrict__ xl = x + lane;

    float a[4] = {0.f, 0.f, 0.f, 0.f};

    for (int ch = 0; ch < nch; ++ch) {
        u32 c[16];
        u32 w[8];
        #pragma unroll
        for (int k = 0; k < 16; ++k) c[k] = pc[ch * 16 + k];   // scalar (s_load) stream
        #pragma unroll
        for (int k = 0; k < 8; ++k)  w[k] = pv[ch * 8 + k];    // scalar bf16 vals x2

        u32 xv[16];
        #pragma unroll
        for (int k = 0; k < 16; ++k)
            xv[k] = (u32)xl[(size_t)c[k] * EMB_DIM];           // 16 independent 1-VGPR gathers

        #pragma unroll
        for (int k = 0; k < 16; ++k) {
            u32 vb = (k & 1) ? (w[k >> 1] & 0xFFFF0000u) : (w[k >> 1] << 16);
            float vv = __uint_as_float(vb);
            float xf = __uint_as_float(xv[k] << 16);
            a[k & 3] += vv * xf;
        }
    }
    float s = (a[0] + a[1]) + (a[2] + a[3]);

    size_t oidx = (size_t)row * EMB_DIM + lane;
    if (y) {
        y[oidx] = f2bf(s);
    } else {
        float r = (bf2f(e0[oidx]) + bf2f(y1[oidx]) + bf2f(y2[oidx]) + s) * 0.25f;
        out[oidx] = r;
    }
}

// ---------------- fallback (R0 atomic path) ----------------
__global__ void init3_kernel(const float* __restrict__ user_emb,
                             const float* __restrict__ item_emb,
                             float* __restrict__ emb,
                             float* __restrict__ acc,
                             float* __restrict__ nxt) {
    int i = blockIdx.x * blockDim.x + threadIdx.x;
    if (i >= NODE_FLOAT4S) return;
    float4 v = (i < USER_FLOAT4S) ? ((const float4*)user_emb)[i]
                                  : ((const float4*)item_emb)[i - USER_FLOAT4S];
    ((float4*)emb)[i] = v;
    ((float4*)acc)[i] = v;
    ((float4*)nxt)[i] = make_float4(0.f, 0.f, 0.f, 0.f);
}

__global__ void spmm_atomic_kernel(const int* __restrict__ rows,
                                   const int* __restrict__ cols,
                                   const float* __restrict__ vals,
                                   const float* __restrict__ x,
                                   float* __restrict__ y) {
    unsigned tid = blockIdx.x * blockDim.x + threadIdx.x;
    unsigned e  = tid >> 4;
    unsigned d4 = tid & 15u;
    if (e >= N_EDGES) return;
    int r = rows[e]; int c = cols[e]; float v = vals[e];
    float4 xv = ((const float4*)(x + (size_t)c * EMB_DIM))[d4];
    float* yp = y + (size_t)r * EMB_DIM + d4 * 4;
    atomicAdd(yp + 0, v * xv.x);
    atomicAdd(yp + 1, v * xv.y);
    atomicAdd(yp + 2, v * xv.z);
    atomicAdd(yp + 3, v * xv.w);
}

__global__ void acc_kernel(float* __restrict__ acc, const float* __restrict__ nxt,
                           float* __restrict__ zbuf, int do_zero, float scale) {
    int i = blockIdx.x * blockDim.x + threadIdx.x;
    if (i >= NODE_FLOAT4S) return;
    float4 a = ((float4*)acc)[i];
    float4 n = ((const float4*)nxt)[i];
    a.x = (a.x + n.x) * scale; a.y = (a.y + n.y) * scale;
    a.z = (a.z + n.z) * scale; a.w = (a.w + n.w) * scale;
    ((float4*)acc)[i] = a;
    if (do_zero) ((float4*)zbuf)[i] = make_float4(0.f, 0.f, 0.f, 0.f);
}

extern "C" void kernel_launch(void* const* d_in, const int* in_sizes, int n_in,
                              void* d_out, int out_size, void* d_ws, size_t ws_size,
                              hipStream_t stream) {
    const int*   rows     = (const int*)d_in[0];
    const int*   cols     = (const int*)d_in[1];
    const float* vals     = (const float*)d_in[2];
    const float* user_emb = (const float*)d_in[3];
    const float* item_emb = (const float*)d_in[4];
    float* out = (float*)d_out;

    // ws layout (u32 units):
    //   buf0 bf16 [4.8M]
    //   | STAGE region [9.9M]: stage_key [6.6M] + stage_val u16 [3.3M u32]
    //       (after stageB2 the region is dead; buf1 = [0..4.8M), buf2 = [4.8M..9.6M))
    //   | csr_col [6.0M padded] | csr_val u16 [3.0M u32] | desc [150K]
    //   | bx_pos [9376*16] | csr_cursor [16]
    constexpr size_t U_BUF   = (size_t)NODE_FLOATS / 2;   // 4,800,000
    constexpr size_t U_SKEY  = (size_t)SEG * CAP1;        // 6,600,704
    constexpr size_t U_SVAL  = U_SKEY / 2;                // 3,300,352
    constexpr size_t U_STAGE = U_SKEY + U_SVAL;           // 9,901,056 (>= 9.6M for buf1+buf2)
    constexpr size_t U_CCOL  = (size_t)CSR_CAP;           // 6,000,000
    constexpr size_t U_CVAL  = (size_t)CSR_CAP / 2;       // 3,000,000
    size_t need_u32 = U_BUF + U_STAGE + U_CCOL + U_CVAL + (size_t)N_NODES
                    + (size_t)SEG * 16 + 16;

    const int EW_BLOCKS = (NODE_FLOAT4S + 255) / 256;

    if (ws_size >= need_u32 * 4) {
        u32* W = (u32*)d_ws;
        u16* buf0      = (u16*)W;
        u32* stage_key = W + U_BUF;
        u16* stage_val = (u16*)(W + U_BUF + U_SKEY);
        u16* buf1      = (u16*)(W + U_BUF);               // alias: stage [0..4.8M)
        u16* buf2      = (u16*)(W + U_BUF + U_BUF);       // alias: stage [4.8M..9.6M)
        u32* csr_col   = W + U_BUF + U_STAGE;
        u16* csr_val   = (u16*)(csr_col + U_CCOL);
        u32* desc      = (u32*)(csr_col + U_CCOL + U_CVAL);
        int* bx_pos    = (int*)(desc + N_NODES);
        // csr_cursor lives right after bx_pos; zeroed by the same memset

        hipMemsetAsync(bx_pos, 0, ((size_t)SEG * 16 + 16) * sizeof(int), stream);
        stageA2_kernel<<<ABLK2, 256, 0, stream>>>(rows, cols, vals,
                                                  user_emb, item_emb, buf0,
                                                  bx_pos, stage_key, stage_val);
        int* csr_cur = bx_pos + (size_t)SEG * 16;
        stageB2_kernel<<<NB, 256, 0, stream>>>(bx_pos, stage_key, stage_val,
                                               csr_cur, csr_col, csr_val, desc);

        const int SPMM_BLOCKS = (N_NODES + 3) / 4;        // 4 rows (waves) per block
        spmm_rw_kernel<<<SPMM_BLOCKS, 256, 0, stream>>>(desc, csr_col, csr_val,
                                                        buf0, buf1, nullptr, nullptr, nullptr, nullptr);
        spmm_rw_kernel<<<SPMM_BLOCKS, 256, 0, stream>>>(desc, csr_col, csr_val,
                                                        buf1, buf2, nullptr, nullptr, nullptr, nullptr);
        spmm_rw_kernel<<<SPMM_BLOCKS, 256, 0, stream>>>(desc, csr_col, csr_val,
                                                        buf2, nullptr, buf0, buf1, buf2, out);
    } else {
        // fallback: R0 atomic path
        float* buf0 = (float*)d_ws;
        float* buf1 = buf0 + NODE_FLOATS;
        const int SPMM_BLOCKS = (int)(((size_t)N_EDGES * 16 + 255) / 256);
        init3_kernel<<<EW_BLOCKS, 256, 0, stream>>>(user_emb, item_emb, buf0, out, buf1);
        float* prev = buf0; float* next = buf1;
        for (int layer = 0; layer < 3; ++layer) {
            spmm_atomic_kernel<<<SPMM_BLOCKS, 256, 0, stream>>>(rows, cols, vals, prev, next);
            if (layer < 2) acc_kernel<<<EW_BLOCKS, 256, 0, stream>>>(out, next, prev, 1, 1.0f);
            else           acc_kernel<<<EW_BLOCKS, 256, 0, stream>>>(out, next, prev, 0, 0.25f);
            float* t = prev; prev = next; next = t;
        }
    }
}